// Round 2
// baseline (1567.556 us; speedup 1.0000x reference)
//
#include <hip/hip_runtime.h>
#include <hip/hip_bf16.h>
#include <cstdint>
#include <cstddef>

#define NN 50000
#define NE 400000
typedef long long i64;

// ---------------- setup kernels ----------------
__global__ void k_init(int* __restrict__ deg, int* __restrict__ flag) {
    int i = blockIdx.x * blockDim.x + threadIdx.x;
    if (i < NN) deg[i] = 0;
    if (i == 0) *flag = 0;
}

// Detect edge dtype: if buffer is int64, all int64-views in [0,NN). If it is
// int32, pairs combine to huge values -> flag=1 (int32). Reads exactly NE*8 =
// 3.2MB, safe for both layouts.
__global__ void k_detect(const void* __restrict__ ei, int* __restrict__ flag) {
    int i = blockIdx.x * blockDim.x + threadIdx.x;
    if (i < NE) {
        i64 v = ((const i64*)ei)[i];
        if (v < 0 || v >= NN) atomicOr(flag, 1);
    }
}

__device__ inline int edge_at(const void* ei, int f32idx, int half, int i) {
    if (f32idx) return ((const int*)ei)[half * NE + i];
    return (int)((const i64*)ei)[half * NE + i];
}

__global__ void k_hist(const void* __restrict__ ei, const int* __restrict__ flag,
                       int* __restrict__ deg) {
    int i = blockIdx.x * blockDim.x + threadIdx.x;
    if (i < NE) {
        int d = edge_at(ei, *flag, 1, i);
        if ((unsigned)d < NN) atomicAdd(&deg[d], 1);
    }
}

__global__ void k_node_setup(const int* __restrict__ deg, float* __restrict__ inv_sqrt,
                             float* __restrict__ inv_deg) {
    int i = blockIdx.x * blockDim.x + threadIdx.x;
    if (i < NN) {
        float d = (float)deg[i] + 1.0f;
        inv_sqrt[i] = rsqrtf(d);
        inv_deg[i]  = 1.0f / d;
    }
}

#define SCAN_T 256
#define SCAN_CH 196  // 256*196 = 50176 >= 50000
__global__ __launch_bounds__(SCAN_T) void k_scan(const int* __restrict__ deg,
                                                 int* __restrict__ row_off,
                                                 int* __restrict__ cursor) {
    __shared__ int ssum[SCAN_T];
    int t = threadIdx.x;
    int base = t * SCAN_CH;
    int s = 0;
    for (int i = 0; i < SCAN_CH; i++) {
        int idx = base + i;
        if (idx < NN) s += deg[idx];
    }
    ssum[t] = s;
    __syncthreads();
    for (int off = 1; off < SCAN_T; off <<= 1) {
        int v = (t >= off) ? ssum[t - off] : 0;
        __syncthreads();
        ssum[t] += v;
        __syncthreads();
    }
    int run = (t == 0) ? 0 : ssum[t - 1];
    for (int i = 0; i < SCAN_CH; i++) {
        int idx = base + i;
        if (idx < NN) {
            row_off[idx] = run;
            cursor[idx]  = run;
            run += deg[idx];
        }
    }
    if (t == SCAN_T - 1) row_off[NN] = run;  // total valid edges
}

__global__ void k_scatter(const void* __restrict__ ei, const int* __restrict__ flag,
                          const float* __restrict__ inv_sqrt,
                          int* __restrict__ cursor, int* __restrict__ ssrc,
                          float* __restrict__ snorm) {
    int i = blockIdx.x * blockDim.x + threadIdx.x;
    if (i < NE) {
        int f = *flag;
        int s = edge_at(ei, f, 0, i);
        int d = edge_at(ei, f, 1, i);
        if ((unsigned)s < NN && (unsigned)d < NN) {
            int pos = atomicAdd(&cursor[d], 1);
            if ((unsigned)pos < NE) {
                ssrc[pos]  = s;
                snorm[pos] = inv_sqrt[s] * inv_sqrt[d];
            }
        }
    }
}

// ---------------- CSR aggregation ----------------
template <int W, int VEC, bool BIAS, bool RELU>
__global__ void k_agg(const float* __restrict__ X, float* __restrict__ Y,
                      const int* __restrict__ row_off, const int* __restrict__ ssrc,
                      const float* __restrict__ snorm, const float* __restrict__ inv_deg,
                      const float* __restrict__ bias) {
    int node = blockIdx.x;
    int col = threadIdx.x * VEC;
    int beg = row_off[node], end = row_off[node + 1];
    float acc[VEC];
#pragma unroll
    for (int v = 0; v < VEC; v++) acc[v] = 0.f;

    for (int e = beg; e < end; e++) {
        int s = ssrc[e];
        if ((unsigned)s >= NN) continue;  // guard against any bad index
        float nm = snorm[e];
        const float* r = X + (size_t)s * W + col;
        if constexpr (VEC == 4) {
            float4 t = *(const float4*)r;
            acc[0] = fmaf(t.x, nm, acc[0]);
            acc[1] = fmaf(t.y, nm, acc[1]);
            acc[2] = fmaf(t.z, nm, acc[2]);
            acc[3] = fmaf(t.w, nm, acc[3]);
        } else {
            float2 t = *(const float2*)r;
            acc[0] = fmaf(t.x, nm, acc[0]);
            acc[1] = fmaf(t.y, nm, acc[1]);
        }
    }
    {   // self-loop: d^-1 * h_i
        float idg = inv_deg[node];
        const float* r = X + (size_t)node * W + col;
        if constexpr (VEC == 4) {
            float4 t = *(const float4*)r;
            acc[0] = fmaf(t.x, idg, acc[0]);
            acc[1] = fmaf(t.y, idg, acc[1]);
            acc[2] = fmaf(t.z, idg, acc[2]);
            acc[3] = fmaf(t.w, idg, acc[3]);
        } else {
            float2 t = *(const float2*)r;
            acc[0] = fmaf(t.x, idg, acc[0]);
            acc[1] = fmaf(t.y, idg, acc[1]);
        }
    }
#pragma unroll
    for (int v = 0; v < VEC; v++) {
        float val = acc[v];
        if (BIAS) val += bias[col + v];
        if (RELU) val = fmaxf(val, 0.f);
        Y[(size_t)node * W + col + v] = val;
    }
}

// ---------------- f32 tiled GEMM (vector ALU; no fp32 MFMA on CDNA4) ----------------
#define TBM 64
#define TBN 64
#define TBK 16
#define LPAD 4

template <bool BIAS, bool RELU>
__global__ __launch_bounds__(256) void gemm_kernel(
    const float* __restrict__ A, const float* __restrict__ B,
    const float* __restrict__ bias, float* __restrict__ C,
    int M, int N, int K) {
    __shared__ float As[TBK][TBM + LPAD];
    __shared__ float Bs[TBK][TBN + LPAD];
    const int bm = blockIdx.y * TBM;
    const int bn = blockIdx.x * TBN;
    const int tid = threadIdx.x;
    const int tx = tid & 15;
    const int ty = tid >> 4;
    const int la_m = tid >> 2;
    const int la_k = (tid & 3) << 2;
    const int lb_k = tid >> 4;
    const int lb_n = (tid & 15) << 2;

    float acc[4][4];
#pragma unroll
    for (int i = 0; i < 4; i++)
#pragma unroll
        for (int j = 0; j < 4; j++) acc[i][j] = 0.f;

    const int am = bm + la_m;
    const bool a_ok = am < M;
    const int bng = bn + lb_n;

    for (int k0 = 0; k0 < K; k0 += TBK) {
        float4 av = make_float4(0.f, 0.f, 0.f, 0.f);
        if (a_ok) av = *(const float4*)(A + (size_t)am * K + k0 + la_k);
        float4 bv = make_float4(0.f, 0.f, 0.f, 0.f);
        {
            const float* Bp = B + (size_t)(k0 + lb_k) * N + bng;
            if (bng + 3 < N) {
                bv = *(const float4*)Bp;
            } else {
                if (bng + 0 < N) bv.x = Bp[0];
                if (bng + 1 < N) bv.y = Bp[1];
                if (bng + 2 < N) bv.z = Bp[2];
            }
        }
        As[la_k + 0][la_m] = av.x;
        As[la_k + 1][la_m] = av.y;
        As[la_k + 2][la_m] = av.z;
        As[la_k + 3][la_m] = av.w;
        *(float4*)&Bs[lb_k][lb_n] = bv;
        __syncthreads();
#pragma unroll
        for (int k = 0; k < TBK; k++) {
            float4 a = *(const float4*)&As[k][ty << 2];
            float4 b = *(const float4*)&Bs[k][tx << 2];
            float aa[4] = {a.x, a.y, a.z, a.w};
            float bb[4] = {b.x, b.y, b.z, b.w};
#pragma unroll
            for (int i = 0; i < 4; i++)
#pragma unroll
                for (int j = 0; j < 4; j++)
                    acc[i][j] = fmaf(aa[i], bb[j], acc[i][j]);
        }
        __syncthreads();
    }
#pragma unroll
    for (int i = 0; i < 4; i++) {
        int m = bm + (ty << 2) + i;
        if (m < M) {
#pragma unroll
            for (int j = 0; j < 4; j++) {
                int n = bn + (tx << 2) + j;
                if (n < N) {
                    float v = acc[i][j];
                    if (BIAS) v += bias[n];
                    if (RELU) v = fmaxf(v, 0.f);
                    C[(size_t)m * N + n] = v;
                }
            }
        }
    }
}

// ---------------- launch ----------------
// Workspace budget (~235 MB):
//   small arrays ~4.2 MB
//   region1 [N,512] f32 : t2, later g3
//   region2 [N,512] f32 : h1-chunk (25000x1024), later h2
//   region3 [N,128] f32 : a0, later h3
extern "C" void kernel_launch(void* const* d_in, const int* in_sizes, int n_in,
                              void* d_out, int out_size, void* d_ws, size_t ws_size,
                              hipStream_t stream) {
    const float* x   = (const float*)d_in[0];
    const void*  ei  = d_in[1];
    const float* W1  = (const float*)d_in[2];
    const float* b1  = (const float*)d_in[3];
    const float* W2  = (const float*)d_in[4];
    const float* b2  = (const float*)d_in[5];
    const float* W3  = (const float*)d_in[6];
    const float* b3  = (const float*)d_in[7];
    const float* Wfc = (const float*)d_in[8];
    const float* bfc = (const float*)d_in[9];
    float* out = (float*)d_out;

    char* ws = (char*)d_ws;
    size_t off = 0;
    auto take = [&](size_t bytes) -> void* {
        off = (off + 255) & ~(size_t)255;
        void* p = ws + off;
        off += bytes;
        return p;
    };
    int*   deg     = (int*)take((size_t)NN * 4);
    int*   row_off = (int*)take((size_t)(NN + 1) * 4);
    int*   cursor  = (int*)take((size_t)NN * 4);
    float* isq     = (float*)take((size_t)NN * 4);
    float* idg     = (float*)take((size_t)NN * 4);
    int*   ssrc    = (int*)take((size_t)NE * 4);
    float* snorm   = (float*)take((size_t)NE * 4);
    int*   flag    = (int*)take(256);
    float* region1 = (float*)take((size_t)NN * 512 * 4);  // t2 / g3
    float* region2 = (float*)take((size_t)NN * 512 * 4);  // h1-chunk / h2
    float* region3 = (float*)take((size_t)NN * 128 * 4);  // a0 / h3

    // graph setup
    k_init<<<(NN + 255) / 256, 256, 0, stream>>>(deg, flag);
    k_detect<<<(NE + 255) / 256, 256, 0, stream>>>(ei, flag);
    k_hist<<<(NE + 255) / 256, 256, 0, stream>>>(ei, flag, deg);
    k_node_setup<<<(NN + 255) / 256, 256, 0, stream>>>(deg, isq, idg);
    k_scan<<<1, SCAN_T, 0, stream>>>(deg, row_off, cursor);
    k_scatter<<<(NE + 255) / 256, 256, 0, stream>>>(ei, flag, isq, cursor, ssrc, snorm);

    // L1: aggregate on input width (128)
    float* a0 = region3;
    k_agg<128, 2, false, false><<<NN, 64, 0, stream>>>(x, a0, row_off, ssrc, snorm, idg, nullptr);

    // L1-GEMM -> L2-GEMM fused over row chunks (h1 never fully materialized)
    float* t2   = region1;
    float* hbuf = region2;  // CH x 1024; CH*4096B == region2 size
    const int CH = 25000;
    for (int r0 = 0; r0 < NN; r0 += CH) {
        int cm = (NN - r0 < CH) ? (NN - r0) : CH;
        int mb = (cm + TBM - 1) / TBM;
        gemm_kernel<true, true><<<dim3(1024 / TBN, mb), 256, 0, stream>>>(
            a0 + (size_t)r0 * 128, W1, b1, hbuf, cm, 1024, 128);
        gemm_kernel<false, false><<<dim3(512 / TBN, mb), 256, 0, stream>>>(
            hbuf, W2, nullptr, t2 + (size_t)r0 * 512, cm, 512, 1024);
    }

    // L2 aggregation (+b2 +relu)
    float* h2 = region2;  // hbuf dead
    k_agg<512, 4, true, true><<<NN, 128, 0, stream>>>(t2, h2, row_off, ssrc, snorm, idg, b2);

    // L3: GEMM then aggregate (+b3 +relu)
    float* g3 = region1;  // t2 dead
    {
        int mb = (NN + TBM - 1) / TBM;
        gemm_kernel<false, false><<<dim3(128 / TBN, mb), 256, 0, stream>>>(h2, W3, nullptr, g3, NN, 128, 512);
    }
    float* h3 = region3;  // a0 dead
    k_agg<128, 2, true, true><<<NN, 64, 0, stream>>>(g3, h3, row_off, ssrc, snorm, idg, b3);

    // FC
    {
        int mb = (NN + TBM - 1) / TBM;
        gemm_kernel<true, false><<<dim3(1, mb), 256, 0, stream>>>(h3, Wfc, bfc, out, NN, 40, 128);
    }

    (void)in_sizes; (void)n_in; (void)out_size; (void)ws_size;
}

// Round 3
// 615.565 us; speedup vs baseline: 2.5465x; 2.5465x over previous
//
#include <hip/hip_runtime.h>
#include <hip/hip_bf16.h>
#include <cstdint>
#include <cstddef>

#define NN 50000
#define NE 400000
typedef long long i64;
typedef unsigned short u16;
typedef __attribute__((ext_vector_type(8))) short bf16x8;
typedef __attribute__((ext_vector_type(8))) unsigned short u16x8;
typedef __attribute__((ext_vector_type(4))) float f32x4;

__device__ inline u16 f2bf(float f) {  // RNE
    unsigned u = __float_as_uint(f);
    u += 0x7fffu + ((u >> 16) & 1u);
    return (u16)(u >> 16);
}
__device__ inline float bf2f(u16 b) { return __uint_as_float(((unsigned)b) << 16); }

// ---------------- setup kernels ----------------
__global__ void k_init(int* __restrict__ deg, int* __restrict__ flag) {
    int i = blockIdx.x * blockDim.x + threadIdx.x;
    if (i < NN) deg[i] = 0;
    if (i == 0) *flag = 0;
}

__global__ void k_detect(const void* __restrict__ ei, int* __restrict__ flag) {
    int i = blockIdx.x * blockDim.x + threadIdx.x;
    if (i < NE) {
        i64 v = ((const i64*)ei)[i];
        if (v < 0 || v >= NN) atomicOr(flag, 1);
    }
}

__device__ inline int edge_at(const void* ei, int f32idx, int half, int i) {
    if (f32idx) return ((const int*)ei)[half * NE + i];
    return (int)((const i64*)ei)[half * NE + i];
}

__global__ void k_hist(const void* __restrict__ ei, const int* __restrict__ flag,
                       int* __restrict__ deg) {
    int i = blockIdx.x * blockDim.x + threadIdx.x;
    if (i < NE) {
        int d = edge_at(ei, *flag, 1, i);
        if ((unsigned)d < NN) atomicAdd(&deg[d], 1);
    }
}

__global__ void k_node_setup(const int* __restrict__ deg, float* __restrict__ inv_sqrt,
                             float* __restrict__ inv_deg) {
    int i = blockIdx.x * blockDim.x + threadIdx.x;
    if (i < NN) {
        float d = (float)deg[i] + 1.0f;
        inv_sqrt[i] = rsqrtf(d);
        inv_deg[i]  = 1.0f / d;
    }
}

#define SCAN_T 256
#define SCAN_CH 196
__global__ __launch_bounds__(SCAN_T) void k_scan(const int* __restrict__ deg,
                                                 int* __restrict__ row_off,
                                                 int* __restrict__ cursor) {
    __shared__ int ssum[SCAN_T];
    int t = threadIdx.x;
    int base = t * SCAN_CH;
    int s = 0;
    for (int i = 0; i < SCAN_CH; i++) {
        int idx = base + i;
        if (idx < NN) s += deg[idx];
    }
    ssum[t] = s;
    __syncthreads();
    for (int off = 1; off < SCAN_T; off <<= 1) {
        int v = (t >= off) ? ssum[t - off] : 0;
        __syncthreads();
        ssum[t] += v;
        __syncthreads();
    }
    int run = (t == 0) ? 0 : ssum[t - 1];
    for (int i = 0; i < SCAN_CH; i++) {
        int idx = base + i;
        if (idx < NN) {
            row_off[idx] = run;
            cursor[idx]  = run;
            run += deg[idx];
        }
    }
    if (t == SCAN_T - 1) row_off[NN] = run;
}

__global__ void k_scatter(const void* __restrict__ ei, const int* __restrict__ flag,
                          const float* __restrict__ inv_sqrt,
                          int* __restrict__ cursor, int* __restrict__ ssrc,
                          float* __restrict__ snorm) {
    int i = blockIdx.x * blockDim.x + threadIdx.x;
    if (i < NE) {
        int f = *flag;
        int s = edge_at(ei, f, 0, i);
        int d = edge_at(ei, f, 1, i);
        if ((unsigned)s < NN && (unsigned)d < NN) {
            int pos = atomicAdd(&cursor[d], 1);
            if ((unsigned)pos < NE) {
                ssrc[pos]  = s;
                snorm[pos] = inv_sqrt[s] * inv_sqrt[d];
            }
        }
    }
}

// ---------------- weight convert + transpose: Wt[n][k] = bf16(W[k][n]) ----------------
__global__ void k_wt(const float* __restrict__ W, u16* __restrict__ Wt, int K, int N) {
    int i = blockIdx.x * 256 + threadIdx.x;
    if (i < K * N) {
        int k = i / N, n = i - k * N;  // N is pow2 here but keep generic
        Wt[(size_t)n * K + k] = f2bf(W[i]);
    }
}

// ---------------- CSR aggregation ----------------
// One wave per node. TIN/TOUT: 0=f32, 1=bf16. W in {128,512}; per-lane E = W/64.
template <int W, int TIN, int TOUT, bool BIAS, bool RELU>
__global__ __launch_bounds__(64) void k_agg(const void* __restrict__ Xv, void* __restrict__ Yv,
                      const int* __restrict__ row_off, const int* __restrict__ ssrc,
                      const float* __restrict__ snorm, const float* __restrict__ inv_deg,
                      const float* __restrict__ bias) {
    constexpr int E = W / 64;
    int node = blockIdx.x;
    int lane = threadIdx.x;
    int col = lane * E;
    int beg = row_off[node], end = row_off[node + 1];
    float acc[E];
#pragma unroll
    for (int v = 0; v < E; v++) acc[v] = 0.f;

    auto accum = [&](int srow, float w) {
        if constexpr (TIN == 0) {
            const float* r = (const float*)Xv + (size_t)srow * W + col;
            if constexpr (E == 2) {
                float2 t = *(const float2*)r;
                acc[0] = fmaf(t.x, w, acc[0]);
                acc[1] = fmaf(t.y, w, acc[1]);
            } else {
                float4 t0 = *(const float4*)r;
                float4 t1 = *(const float4*)(r + 4);
                acc[0] = fmaf(t0.x, w, acc[0]); acc[1] = fmaf(t0.y, w, acc[1]);
                acc[2] = fmaf(t0.z, w, acc[2]); acc[3] = fmaf(t0.w, w, acc[3]);
                acc[4] = fmaf(t1.x, w, acc[4]); acc[5] = fmaf(t1.y, w, acc[5]);
                acc[6] = fmaf(t1.z, w, acc[6]); acc[7] = fmaf(t1.w, w, acc[7]);
            }
        } else {
            const u16* r = (const u16*)Xv + (size_t)srow * W + col;
            if constexpr (E == 2) {
                unsigned t = *(const unsigned*)r;
                acc[0] = fmaf(bf2f((u16)(t & 0xffff)), w, acc[0]);
                acc[1] = fmaf(bf2f((u16)(t >> 16)), w, acc[1]);
            } else {
                u16x8 t = *(const u16x8*)r;
#pragma unroll
                for (int j = 0; j < 8; j++) acc[j] = fmaf(bf2f(t[j]), w, acc[j]);
            }
        }
    };

    for (int e = beg; e < end; e++) {
        int s = ssrc[e];
        if ((unsigned)s >= NN) continue;
        accum(s, snorm[e]);
    }
    accum(node, inv_deg[node]);

#pragma unroll
    for (int v = 0; v < E; v++) {
        float val = acc[v];
        if (BIAS) val += bias[col + v];
        if (RELU) val = fmaxf(val, 0.f);
        if constexpr (TOUT == 0) ((float*)Yv)[(size_t)node * W + col + v] = val;
        else ((u16*)Yv)[(size_t)node * W + col + v] = f2bf(val);
    }
}

// ---------------- bf16 MFMA GEMM: C[M][N] = A[M][K] * Bt[N][K]^T ----------------
// 128x128 tile, BK=32, 4 waves (2x2), 16x16x32 MFMA, global_load_lds staging.
#define GBM 128
#define GBN 128
#define GBK 32

#define LDS_AS(p) ((__attribute__((address_space(3))) void*)(p))
#define GLB_AS(p) ((const __attribute__((address_space(1))) void*)(p))

template <bool BIAS, bool RELU>
__global__ __launch_bounds__(256) void mfma_gemm(
    const u16* __restrict__ A,   // [M][K] bf16
    const u16* __restrict__ Bt,  // [N][K] bf16
    const float* __restrict__ bias,  // [N] or null
    u16* __restrict__ C,         // [M][N] bf16
    int M, int N, int K) {
    __shared__ __align__(16) u16 As[GBM * GBK];  // 8KB
    __shared__ __align__(16) u16 Bs[GBN * GBK];  // 8KB
    const int tid = threadIdx.x;
    const int lane = tid & 63;
    const int wave = tid >> 6;
    const int wr = wave >> 1, wc = wave & 1;
    const int bm = blockIdx.y * GBM;
    const int bn = blockIdx.x * GBN;

    f32x4 acc[4][4];
#pragma unroll
    for (int m = 0; m < 4; m++)
#pragma unroll
        for (int n = 0; n < 4; n++) acc[m][n] = (f32x4)0.f;

    // staging: each thread loads 16B at tile-byte-offset o and o+4096 (tile = 8KB)
    const int o = tid * 16;
    const int row0 = o >> 6;             // 64 bytes per LDS row (32 bf16)
    const int colb = o & 63;
    const int row1 = row0 + 64;          // (o+4096)>>6

    int ar0 = bm + row0; if (ar0 >= M) ar0 = M - 1;
    int ar1 = bm + row1; if (ar1 >= M) ar1 = M - 1;
    const int br0 = bn + row0;
    const int br1 = bn + row1;
    const size_t sK = (size_t)K * 2;     // row stride bytes

    const char* Ab = (const char*)A;
    const char* Bb = (const char*)Bt;

    const int kc = (lane >> 4) << 3;     // 0,8,16,24
    const int fr = lane & 15;
    const u16* ApA = &As[(wr * 64 + fr) * GBK + kc];
    const u16* BpB = &Bs[(wc * 64 + fr) * GBK + kc];

    for (int k0 = 0; k0 < K; k0 += GBK) {
        const size_t kb = (size_t)k0 * 2 + colb;
        __builtin_amdgcn_global_load_lds(GLB_AS(Ab + (size_t)ar0 * sK + kb), LDS_AS((char*)As + o), 16, 0, 0);
        __builtin_amdgcn_global_load_lds(GLB_AS(Ab + (size_t)ar1 * sK + kb), LDS_AS((char*)As + o + 4096), 16, 0, 0);
        __builtin_amdgcn_global_load_lds(GLB_AS(Bb + (size_t)br0 * sK + kb), LDS_AS((char*)Bs + o), 16, 0, 0);
        __builtin_amdgcn_global_load_lds(GLB_AS(Bb + (size_t)br1 * sK + kb), LDS_AS((char*)Bs + o + 4096), 16, 0, 0);
        __syncthreads();

        bf16x8 af[4], bfr[4];
#pragma unroll
        for (int m = 0; m < 4; m++) af[m] = *(const bf16x8*)(ApA + m * 16 * GBK);
#pragma unroll
        for (int n = 0; n < 4; n++) bfr[n] = *(const bf16x8*)(BpB + n * 16 * GBK);
#pragma unroll
        for (int m = 0; m < 4; m++)
#pragma unroll
            for (int n = 0; n < 4; n++)
                acc[m][n] = __builtin_amdgcn_mfma_f32_16x16x32_bf16(af[m], bfr[n], acc[m][n], 0, 0, 0);
        __syncthreads();
    }

    // epilogue: C/D layout col=lane&15, row=4*(lane>>4)+reg
    const int cr = (lane >> 4) << 2;
    const int cc = lane & 15;
#pragma unroll
    for (int n = 0; n < 4; n++) {
        int col = bn + wc * 64 + n * 16 + cc;
        float bv = BIAS ? bias[col] : 0.f;
#pragma unroll
        for (int m = 0; m < 4; m++) {
#pragma unroll
            for (int j = 0; j < 4; j++) {
                int row = bm + wr * 64 + m * 16 + cr + j;
                if (row < M) {
                    float v = acc[m][n][j] + bv;
                    if (RELU) v = fmaxf(v, 0.f);
                    C[(size_t)row * N + col] = f2bf(v);
                }
            }
        }
    }
}

// ---------------- f32 tiled GEMM (kept for the small FC layer) ----------------
#define TBM 64
#define TBN 64
#define TBK 16
#define LPAD 4

template <bool BIAS, bool RELU>
__global__ __launch_bounds__(256) void gemm_kernel(
    const float* __restrict__ A, const float* __restrict__ B,
    const float* __restrict__ bias, float* __restrict__ C,
    int M, int N, int K) {
    __shared__ float Asl[TBK][TBM + LPAD];
    __shared__ float Bsl[TBK][TBN + LPAD];
    const int bm = blockIdx.y * TBM;
    const int bn = blockIdx.x * TBN;
    const int tid = threadIdx.x;
    const int tx = tid & 15;
    const int ty = tid >> 4;
    const int la_m = tid >> 2;
    const int la_k = (tid & 3) << 2;
    const int lb_k = tid >> 4;
    const int lb_n = (tid & 15) << 2;

    float acc[4][4];
#pragma unroll
    for (int i = 0; i < 4; i++)
#pragma unroll
        for (int j = 0; j < 4; j++) acc[i][j] = 0.f;

    const int am = bm + la_m;
    const bool a_ok = am < M;
    const int bng = bn + lb_n;

    for (int k0 = 0; k0 < K; k0 += TBK) {
        float4 av = make_float4(0.f, 0.f, 0.f, 0.f);
        if (a_ok) av = *(const float4*)(A + (size_t)am * K + k0 + la_k);
        float4 bv = make_float4(0.f, 0.f, 0.f, 0.f);
        {
            const float* Bp = B + (size_t)(k0 + lb_k) * N + bng;
            if (bng + 3 < N) {
                bv = *(const float4*)Bp;
            } else {
                if (bng + 0 < N) bv.x = Bp[0];
                if (bng + 1 < N) bv.y = Bp[1];
                if (bng + 2 < N) bv.z = Bp[2];
            }
        }
        Asl[la_k + 0][la_m] = av.x;
        Asl[la_k + 1][la_m] = av.y;
        Asl[la_k + 2][la_m] = av.z;
        Asl[la_k + 3][la_m] = av.w;
        *(float4*)&Bsl[lb_k][lb_n] = bv;
        __syncthreads();
#pragma unroll
        for (int k = 0; k < TBK; k++) {
            float4 a = *(const float4*)&Asl[k][ty << 2];
            float4 b = *(const float4*)&Bsl[k][tx << 2];
            float aa[4] = {a.x, a.y, a.z, a.w};
            float bb[4] = {b.x, b.y, b.z, b.w};
#pragma unroll
            for (int i = 0; i < 4; i++)
#pragma unroll
                for (int j = 0; j < 4; j++)
                    acc[i][j] = fmaf(aa[i], bb[j], acc[i][j]);
        }
        __syncthreads();
    }
#pragma unroll
    for (int i = 0; i < 4; i++) {
        int m = bm + (ty << 2) + i;
        if (m < M) {
#pragma unroll
            for (int j = 0; j < 4; j++) {
                int n = bn + (tx << 2) + j;
                if (n < N) {
                    float v = acc[i][j];
                    if (BIAS) v += bias[n];
                    if (RELU) v = fmaxf(v, 0.f);
                    C[(size_t)m * N + n] = v;
                }
            }
        }
    }
}

// ---------------- launch ----------------
extern "C" void kernel_launch(void* const* d_in, const int* in_sizes, int n_in,
                              void* d_out, int out_size, void* d_ws, size_t ws_size,
                              hipStream_t stream) {
    const float* x   = (const float*)d_in[0];
    const void*  ei  = d_in[1];
    const float* W1  = (const float*)d_in[2];
    const float* b1  = (const float*)d_in[3];
    const float* W2  = (const float*)d_in[4];
    const float* b2  = (const float*)d_in[5];
    const float* W3  = (const float*)d_in[6];
    const float* b3  = (const float*)d_in[7];
    const float* Wfc = (const float*)d_in[8];
    const float* bfc = (const float*)d_in[9];
    float* out = (float*)d_out;

    char* ws = (char*)d_ws;
    size_t off = 0;
    auto take = [&](size_t bytes) -> void* {
        off = (off + 255) & ~(size_t)255;
        void* p = ws + off;
        off += bytes;
        return p;
    };
    int*   deg     = (int*)take((size_t)NN * 4);
    int*   row_off = (int*)take((size_t)(NN + 1) * 4);
    int*   cursor  = (int*)take((size_t)NN * 4);
    float* isq     = (float*)take((size_t)NN * 4);
    float* idg     = (float*)take((size_t)NN * 4);
    int*   ssrc    = (int*)take((size_t)NE * 4);
    float* snorm   = (float*)take((size_t)NE * 4);
    int*   flag    = (int*)take(256);
    u16*   Wt1     = (u16*)take((size_t)1024 * 128 * 2);
    u16*   Wt2     = (u16*)take((size_t)512 * 1024 * 2);
    u16*   Wt3     = (u16*)take((size_t)128 * 512 * 2);
    u16*   rA      = (u16*)take((size_t)NN * 128 * 2);   // a0, later g3
    u16*   rH      = (u16*)take((size_t)NN * 1024 * 2);  // h1, later h2
    u16*   rT      = (u16*)take((size_t)NN * 512 * 2);   // t2
    float* h3      = (float*)take((size_t)NN * 128 * 4);

    // graph setup
    k_init<<<(NN + 255) / 256, 256, 0, stream>>>(deg, flag);
    k_detect<<<(NE + 255) / 256, 256, 0, stream>>>(ei, flag);
    k_hist<<<(NE + 255) / 256, 256, 0, stream>>>(ei, flag, deg);
    k_node_setup<<<(NN + 255) / 256, 256, 0, stream>>>(deg, isq, idg);
    k_scan<<<1, SCAN_T, 0, stream>>>(deg, row_off, cursor);
    k_scatter<<<(NE + 255) / 256, 256, 0, stream>>>(ei, flag, isq, cursor, ssrc, snorm);

    // weights -> bf16 transposed
    k_wt<<<(128 * 1024 + 255) / 256, 256, 0, stream>>>(W1, Wt1, 128, 1024);
    k_wt<<<(1024 * 512 + 255) / 256, 256, 0, stream>>>(W2, Wt2, 1024, 512);
    k_wt<<<(512 * 128 + 255) / 256, 256, 0, stream>>>(W3, Wt3, 512, 128);

    const int MB = (NN + GBM - 1) / GBM;  // 391

    // L1: aggregate x (f32 -> bf16), GEMM(+b1,relu) -> h1
    u16* a0 = rA;
    k_agg<128, 0, 1, false, false><<<NN, 64, 0, stream>>>(x, a0, row_off, ssrc, snorm, idg, nullptr);
    u16* h1 = rH;
    mfma_gemm<true, true><<<dim3(1024 / GBN, MB), 256, 0, stream>>>(a0, Wt1, b1, h1, NN, 1024, 128);

    // L2: GEMM -> t2, aggregate(+b2,relu) -> h2
    u16* t2 = rT;
    mfma_gemm<false, false><<<dim3(512 / GBN, MB), 256, 0, stream>>>(h1, Wt2, nullptr, t2, NN, 512, 1024);
    u16* h2 = rH;  // h1 dead
    k_agg<512, 1, 1, true, true><<<NN, 64, 0, stream>>>(t2, h2, row_off, ssrc, snorm, idg, b2);

    // L3: GEMM -> g3, aggregate(+b3,relu) -> h3 (f32)
    u16* g3 = rA;  // a0 dead
    mfma_gemm<false, false><<<dim3(128 / GBN, MB), 256, 0, stream>>>(h2, Wt3, nullptr, g3, NN, 128, 512);
    k_agg<128, 1, 0, true, true><<<NN, 64, 0, stream>>>(g3, h3, row_off, ssrc, snorm, idg, b3);

    // FC (f32)
    gemm_kernel<true, false><<<dim3(1, (NN + TBM - 1) / TBM), 256, 0, stream>>>(h3, Wfc, bfc, out, NN, 40, 128);

    (void)in_sizes; (void)n_in; (void)out_size; (void)ws_size;
}

// Round 4
// 489.082 us; speedup vs baseline: 3.2051x; 1.2586x over previous
//
#include <hip/hip_runtime.h>
#include <hip/hip_bf16.h>
#include <cstdint>
#include <cstddef>

#define NN 50000
#define NE 400000
typedef long long i64;
typedef unsigned short u16;
typedef __attribute__((ext_vector_type(8))) short bf16x8;
typedef __attribute__((ext_vector_type(8))) unsigned short u16x8;
typedef __attribute__((ext_vector_type(4))) float f32x4;

__device__ inline u16 f2bf(float f) {  // RNE
    unsigned u = __float_as_uint(f);
    u += 0x7fffu + ((u >> 16) & 1u);
    return (u16)(u >> 16);
}
__device__ inline float bf2f(u16 b) { return __uint_as_float(((unsigned)b) << 16); }

// ---------------- setup kernels ----------------
__global__ void k_init(int* __restrict__ deg, int* __restrict__ flag) {
    int i = blockIdx.x * blockDim.x + threadIdx.x;
    if (i < NN) deg[i] = 0;
    if (i == 0) *flag = 0;
}

__global__ void k_detect(const void* __restrict__ ei, int* __restrict__ flag) {
    int i = blockIdx.x * blockDim.x + threadIdx.x;
    if (i < NE) {
        i64 v = ((const i64*)ei)[i];
        if (v < 0 || v >= NN) atomicOr(flag, 1);
    }
}

__device__ inline int edge_at(const void* ei, int f32idx, int half, int i) {
    if (f32idx) return ((const int*)ei)[half * NE + i];
    return (int)((const i64*)ei)[half * NE + i];
}

__global__ void k_hist(const void* __restrict__ ei, const int* __restrict__ flag,
                       int* __restrict__ deg) {
    int i = blockIdx.x * blockDim.x + threadIdx.x;
    if (i < NE) {
        int d = edge_at(ei, *flag, 1, i);
        if ((unsigned)d < NN) atomicAdd(&deg[d], 1);
    }
}

__global__ void k_node_setup(const int* __restrict__ deg, float* __restrict__ inv_sqrt,
                             float* __restrict__ inv_deg) {
    int i = blockIdx.x * blockDim.x + threadIdx.x;
    if (i < NN) {
        float d = (float)deg[i] + 1.0f;
        inv_sqrt[i] = rsqrtf(d);
        inv_deg[i]  = 1.0f / d;
    }
}

// ---------------- 3-phase parallel scan (was: 138us single-block scan) ----------------
#define SB 256
#define NBLK ((NN + SB - 1) / SB)  // 196

__global__ __launch_bounds__(SB) void k_scan1(const int* __restrict__ deg,
                                              int* __restrict__ excl,
                                              int* __restrict__ bsum) {
    __shared__ int s[SB];
    int t = threadIdx.x;
    int i = blockIdx.x * SB + t;
    int v = (i < NN) ? deg[i] : 0;
    s[t] = v;
    __syncthreads();
    for (int off = 1; off < SB; off <<= 1) {
        int x = (t >= off) ? s[t - off] : 0;
        __syncthreads();
        s[t] += x;
        __syncthreads();
    }
    if (i < NN) excl[i] = s[t] - v;
    if (t == SB - 1) bsum[blockIdx.x] = s[t];
}

__global__ __launch_bounds__(SB) void k_scan2(int* __restrict__ bsum) {
    __shared__ int s[SB];
    int t = threadIdx.x;
    int v = (t < NBLK) ? bsum[t] : 0;
    s[t] = v;
    __syncthreads();
    for (int off = 1; off < SB; off <<= 1) {
        int x = (t >= off) ? s[t - off] : 0;
        __syncthreads();
        s[t] += x;
        __syncthreads();
    }
    if (t < NBLK) bsum[t] = s[t] - v;       // exclusive
    if (t == NBLK - 1) bsum[NBLK] = s[t];   // total
}

__global__ __launch_bounds__(SB) void k_scan3(int* __restrict__ row_off,
                                              int* __restrict__ cursor,
                                              const int* __restrict__ bsum) {
    int i = blockIdx.x * SB + threadIdx.x;
    if (i < NN) {
        int r = row_off[i] + bsum[blockIdx.x];
        row_off[i] = r;
        cursor[i]  = r;
    }
    if (i == 0) row_off[NN] = bsum[NBLK];
}

__global__ void k_scatter(const void* __restrict__ ei, const int* __restrict__ flag,
                          const float* __restrict__ inv_sqrt,
                          int* __restrict__ cursor, int* __restrict__ ssrc,
                          float* __restrict__ snorm) {
    int i = blockIdx.x * blockDim.x + threadIdx.x;
    if (i < NE) {
        int f = *flag;
        int s = edge_at(ei, f, 0, i);
        int d = edge_at(ei, f, 1, i);
        if ((unsigned)s < NN && (unsigned)d < NN) {
            int pos = atomicAdd(&cursor[d], 1);
            if ((unsigned)pos < NE) {
                ssrc[pos]  = s;
                snorm[pos] = inv_sqrt[s] * inv_sqrt[d];
            }
        }
    }
}

// ---------------- weight convert + transpose: Wt[n][k] = bf16(W[k][n]) ----------------
__global__ void k_wt(const float* __restrict__ W, u16* __restrict__ Wt, int K, int N) {
    int i = blockIdx.x * 256 + threadIdx.x;
    if (i < K * N) {
        int k = i / N, n = i - k * N;
        Wt[(size_t)n * K + k] = f2bf(W[i]);
    }
}

// ---------------- CSR aggregation ----------------
template <int W, int TIN, int TOUT, bool BIAS, bool RELU>
__global__ __launch_bounds__(64) void k_agg(const void* __restrict__ Xv, void* __restrict__ Yv,
                      const int* __restrict__ row_off, const int* __restrict__ ssrc,
                      const float* __restrict__ snorm, const float* __restrict__ inv_deg,
                      const float* __restrict__ bias) {
    constexpr int E = W / 64;
    int node = blockIdx.x;
    int lane = threadIdx.x;
    int col = lane * E;
    int beg = row_off[node], end = row_off[node + 1];
    float acc[E];
#pragma unroll
    for (int v = 0; v < E; v++) acc[v] = 0.f;

    auto accum = [&](int srow, float w) {
        if constexpr (TIN == 0) {
            const float* r = (const float*)Xv + (size_t)srow * W + col;
            if constexpr (E == 2) {
                float2 t = *(const float2*)r;
                acc[0] = fmaf(t.x, w, acc[0]);
                acc[1] = fmaf(t.y, w, acc[1]);
            } else {
                float4 t0 = *(const float4*)r;
                float4 t1 = *(const float4*)(r + 4);
                acc[0] = fmaf(t0.x, w, acc[0]); acc[1] = fmaf(t0.y, w, acc[1]);
                acc[2] = fmaf(t0.z, w, acc[2]); acc[3] = fmaf(t0.w, w, acc[3]);
                acc[4] = fmaf(t1.x, w, acc[4]); acc[5] = fmaf(t1.y, w, acc[5]);
                acc[6] = fmaf(t1.z, w, acc[6]); acc[7] = fmaf(t1.w, w, acc[7]);
            }
        } else {
            const u16* r = (const u16*)Xv + (size_t)srow * W + col;
            if constexpr (E == 2) {
                unsigned t = *(const unsigned*)r;
                acc[0] = fmaf(bf2f((u16)(t & 0xffff)), w, acc[0]);
                acc[1] = fmaf(bf2f((u16)(t >> 16)), w, acc[1]);
            } else {
                u16x8 t = *(const u16x8*)r;
#pragma unroll
                for (int j = 0; j < 8; j++) acc[j] = fmaf(bf2f(t[j]), w, acc[j]);
            }
        }
    };

    for (int e = beg; e < end; e++) {
        int s = ssrc[e];
        if ((unsigned)s >= NN) continue;
        accum(s, snorm[e]);
    }
    accum(node, inv_deg[node]);

#pragma unroll
    for (int v = 0; v < E; v++) {
        float val = acc[v];
        if (BIAS) val += bias[col + v];
        if (RELU) val = fmaxf(val, 0.f);
        if constexpr (TOUT == 0) ((float*)Yv)[(size_t)node * W + col + v] = val;
        else ((u16*)Yv)[(size_t)node * W + col + v] = f2bf(val);
    }
}

// ---------------- bf16 MFMA GEMM: C[M][N] = A[M][K] * Bt[N][K]^T ----------------
#define GBM 128
#define GBN 128
#define GBK 32

#define LDS_AS(p) ((__attribute__((address_space(3))) void*)(p))
#define GLB_AS(p) ((const __attribute__((address_space(1))) void*)(p))

template <bool BIAS, bool RELU>
__global__ __launch_bounds__(256) void mfma_gemm(
    const u16* __restrict__ A,   // [M][K] bf16
    const u16* __restrict__ Bt,  // [N][K] bf16
    const float* __restrict__ bias,
    u16* __restrict__ C,         // [M][N] bf16
    int M, int N, int K) {
    __shared__ __align__(16) u16 As[GBM * GBK];
    __shared__ __align__(16) u16 Bs[GBN * GBK];
    const int tid = threadIdx.x;
    const int lane = tid & 63;
    const int wave = tid >> 6;
    const int wr = wave >> 1, wc = wave & 1;
    const int bm = blockIdx.y * GBM;
    const int bn = blockIdx.x * GBN;

    f32x4 acc[4][4];
#pragma unroll
    for (int m = 0; m < 4; m++)
#pragma unroll
        for (int n = 0; n < 4; n++) acc[m][n] = (f32x4)0.f;

    const int o = tid * 16;
    const int row0 = o >> 6;
    const int colb = o & 63;
    const int row1 = row0 + 64;

    int ar0 = bm + row0; if (ar0 >= M) ar0 = M - 1;
    int ar1 = bm + row1; if (ar1 >= M) ar1 = M - 1;
    const int br0 = bn + row0;
    const int br1 = bn + row1;
    const size_t sK = (size_t)K * 2;

    const char* Ab = (const char*)A;
    const char* Bb = (const char*)Bt;

    const int kc = (lane >> 4) << 3;
    const int fr = lane & 15;
    const u16* ApA = &As[(wr * 64 + fr) * GBK + kc];
    const u16* BpB = &Bs[(wc * 64 + fr) * GBK + kc];

    for (int k0 = 0; k0 < K; k0 += GBK) {
        const size_t kb = (size_t)k0 * 2 + colb;
        __builtin_amdgcn_global_load_lds(GLB_AS(Ab + (size_t)ar0 * sK + kb), LDS_AS((char*)As + o), 16, 0, 0);
        __builtin_amdgcn_global_load_lds(GLB_AS(Ab + (size_t)ar1 * sK + kb), LDS_AS((char*)As + o + 4096), 16, 0, 0);
        __builtin_amdgcn_global_load_lds(GLB_AS(Bb + (size_t)br0 * sK + kb), LDS_AS((char*)Bs + o), 16, 0, 0);
        __builtin_amdgcn_global_load_lds(GLB_AS(Bb + (size_t)br1 * sK + kb), LDS_AS((char*)Bs + o + 4096), 16, 0, 0);
        __syncthreads();

        bf16x8 af[4], bfr[4];
#pragma unroll
        for (int m = 0; m < 4; m++) af[m] = *(const bf16x8*)(ApA + m * 16 * GBK);
#pragma unroll
        for (int n = 0; n < 4; n++) bfr[n] = *(const bf16x8*)(BpB + n * 16 * GBK);
#pragma unroll
        for (int m = 0; m < 4; m++)
#pragma unroll
            for (int n = 0; n < 4; n++)
                acc[m][n] = __builtin_amdgcn_mfma_f32_16x16x32_bf16(af[m], bfr[n], acc[m][n], 0, 0, 0);
        __syncthreads();
    }

    const int cr = (lane >> 4) << 2;
    const int cc = lane & 15;
#pragma unroll
    for (int n = 0; n < 4; n++) {
        int col = bn + wc * 64 + n * 16 + cc;
        float bv = BIAS ? bias[col] : 0.f;
#pragma unroll
        for (int m = 0; m < 4; m++) {
#pragma unroll
            for (int j = 0; j < 4; j++) {
                int row = bm + wr * 64 + m * 16 + cr + j;
                if (row < M) {
                    float v = acc[m][n][j] + bv;
                    if (RELU) v = fmaxf(v, 0.f);
                    C[(size_t)row * N + col] = f2bf(v);
                }
            }
        }
    }
}

// ---------------- f32 tiled GEMM (small FC layer) ----------------
#define TBM 64
#define TBN 64
#define TBK 16
#define LPAD 4

template <bool BIAS, bool RELU>
__global__ __launch_bounds__(256) void gemm_kernel(
    const float* __restrict__ A, const float* __restrict__ B,
    const float* __restrict__ bias, float* __restrict__ C,
    int M, int N, int K) {
    __shared__ float Asl[TBK][TBM + LPAD];
    __shared__ float Bsl[TBK][TBN + LPAD];
    const int bm = blockIdx.y * TBM;
    const int bn = blockIdx.x * TBN;
    const int tid = threadIdx.x;
    const int tx = tid & 15;
    const int ty = tid >> 4;
    const int la_m = tid >> 2;
    const int la_k = (tid & 3) << 2;
    const int lb_k = tid >> 4;
    const int lb_n = (tid & 15) << 2;

    float acc[4][4];
#pragma unroll
    for (int i = 0; i < 4; i++)
#pragma unroll
        for (int j = 0; j < 4; j++) acc[i][j] = 0.f;

    const int am = bm + la_m;
    const bool a_ok = am < M;
    const int bng = bn + lb_n;

    for (int k0 = 0; k0 < K; k0 += TBK) {
        float4 av = make_float4(0.f, 0.f, 0.f, 0.f);
        if (a_ok) av = *(const float4*)(A + (size_t)am * K + k0 + la_k);
        float4 bv = make_float4(0.f, 0.f, 0.f, 0.f);
        {
            const float* Bp = B + (size_t)(k0 + lb_k) * N + bng;
            if (bng + 3 < N) {
                bv = *(const float4*)Bp;
            } else {
                if (bng + 0 < N) bv.x = Bp[0];
                if (bng + 1 < N) bv.y = Bp[1];
                if (bng + 2 < N) bv.z = Bp[2];
            }
        }
        Asl[la_k + 0][la_m] = av.x;
        Asl[la_k + 1][la_m] = av.y;
        Asl[la_k + 2][la_m] = av.z;
        Asl[la_k + 3][la_m] = av.w;
        *(float4*)&Bsl[lb_k][lb_n] = bv;
        __syncthreads();
#pragma unroll
        for (int k = 0; k < TBK; k++) {
            float4 a = *(const float4*)&Asl[k][ty << 2];
            float4 b = *(const float4*)&Bsl[k][tx << 2];
            float aa[4] = {a.x, a.y, a.z, a.w};
            float bb[4] = {b.x, b.y, b.z, b.w};
#pragma unroll
            for (int i = 0; i < 4; i++)
#pragma unroll
                for (int j = 0; j < 4; j++)
                    acc[i][j] = fmaf(aa[i], bb[j], acc[i][j]);
        }
        __syncthreads();
    }
#pragma unroll
    for (int i = 0; i < 4; i++) {
        int m = bm + (ty << 2) + i;
        if (m < M) {
#pragma unroll
            for (int j = 0; j < 4; j++) {
                int n = bn + (tx << 2) + j;
                if (n < N) {
                    float v = acc[i][j];
                    if (BIAS) v += bias[n];
                    if (RELU) v = fmaxf(v, 0.f);
                    C[(size_t)m * N + n] = v;
                }
            }
        }
    }
}

// ---------------- launch ----------------
extern "C" void kernel_launch(void* const* d_in, const int* in_sizes, int n_in,
                              void* d_out, int out_size, void* d_ws, size_t ws_size,
                              hipStream_t stream) {
    const float* x   = (const float*)d_in[0];
    const void*  ei  = d_in[1];
    const float* W1  = (const float*)d_in[2];
    const float* b1  = (const float*)d_in[3];
    const float* W2  = (const float*)d_in[4];
    const float* b2  = (const float*)d_in[5];
    const float* W3  = (const float*)d_in[6];
    const float* b3  = (const float*)d_in[7];
    const float* Wfc = (const float*)d_in[8];
    const float* bfc = (const float*)d_in[9];
    float* out = (float*)d_out;

    char* ws = (char*)d_ws;
    size_t off = 0;
    auto take = [&](size_t bytes) -> void* {
        off = (off + 255) & ~(size_t)255;
        void* p = ws + off;
        off += bytes;
        return p;
    };
    int*   deg     = (int*)take((size_t)NN * 4);
    int*   row_off = (int*)take((size_t)(NN + 1) * 4);
    int*   cursor  = (int*)take((size_t)NN * 4);
    float* isq     = (float*)take((size_t)NN * 4);
    float* idg     = (float*)take((size_t)NN * 4);
    int*   ssrc    = (int*)take((size_t)NE * 4);
    float* snorm   = (float*)take((size_t)NE * 4);
    int*   flag    = (int*)take(256);
    int*   bsum    = (int*)take((size_t)(NBLK + 1) * 4);
    u16*   Wt1     = (u16*)take((size_t)1024 * 128 * 2);
    u16*   Wt2     = (u16*)take((size_t)512 * 1024 * 2);
    u16*   Wt3     = (u16*)take((size_t)128 * 512 * 2);
    u16*   rA      = (u16*)take((size_t)NN * 128 * 2);   // a0, later g3
    u16*   rH      = (u16*)take((size_t)NN * 1024 * 2);  // h1, later h2
    u16*   rT      = (u16*)take((size_t)NN * 512 * 2);   // t2
    float* h3      = (float*)take((size_t)NN * 128 * 4);

    // graph setup
    k_init<<<(NN + 255) / 256, 256, 0, stream>>>(deg, flag);
    k_detect<<<(NE + 255) / 256, 256, 0, stream>>>(ei, flag);
    k_hist<<<(NE + 255) / 256, 256, 0, stream>>>(ei, flag, deg);
    k_node_setup<<<(NN + 255) / 256, 256, 0, stream>>>(deg, isq, idg);
    k_scan1<<<NBLK, SB, 0, stream>>>(deg, row_off, bsum);
    k_scan2<<<1, SB, 0, stream>>>(bsum);
    k_scan3<<<NBLK, SB, 0, stream>>>(row_off, cursor, bsum);
    k_scatter<<<(NE + 255) / 256, 256, 0, stream>>>(ei, flag, isq, cursor, ssrc, snorm);

    // weights -> bf16 transposed
    k_wt<<<(128 * 1024 + 255) / 256, 256, 0, stream>>>(W1, Wt1, 128, 1024);
    k_wt<<<(1024 * 512 + 255) / 256, 256, 0, stream>>>(W2, Wt2, 1024, 512);
    k_wt<<<(512 * 128 + 255) / 256, 256, 0, stream>>>(W3, Wt3, 512, 128);

    const int MB = (NN + GBM - 1) / GBM;  // 391

    // L1: aggregate x (f32 -> bf16), GEMM(+b1,relu) -> h1
    u16* a0 = rA;
    k_agg<128, 0, 1, false, false><<<NN, 64, 0, stream>>>(x, a0, row_off, ssrc, snorm, idg, nullptr);
    u16* h1 = rH;
    mfma_gemm<true, true><<<dim3(1024 / GBN, MB), 256, 0, stream>>>(a0, Wt1, b1, h1, NN, 1024, 128);

    // L2: GEMM -> t2, aggregate(+b2,relu) -> h2
    u16* t2 = rT;
    mfma_gemm<false, false><<<dim3(512 / GBN, MB), 256, 0, stream>>>(h1, Wt2, nullptr, t2, NN, 512, 1024);
    u16* h2 = rH;  // h1 dead
    k_agg<512, 1, 1, true, true><<<NN, 64, 0, stream>>>(t2, h2, row_off, ssrc, snorm, idg, b2);

    // L3: GEMM -> g3, aggregate(+b3,relu) -> h3 (f32)
    u16* g3 = rA;  // a0 dead
    mfma_gemm<false, false><<<dim3(128 / GBN, MB), 256, 0, stream>>>(h2, Wt3, nullptr, g3, NN, 128, 512);
    k_agg<128, 1, 0, true, true><<<NN, 64, 0, stream>>>(g3, h3, row_off, ssrc, snorm, idg, b3);

    // FC (f32)
    gemm_kernel<true, false><<<dim3(1, (NN + TBM - 1) / TBM), 256, 0, stream>>>(h3, Wfc, bfc, out, NN, 40, 128);

    (void)in_sizes; (void)n_in; (void)out_size; (void)ws_size;
}